// Round 1
// baseline (413.616 us; speedup 1.0000x reference)
//
#include <hip/hip_runtime.h>
#include <stdint.h>

// ---------------------------------------------------------------------------
// torch-ngp hashgrid encode (16 levels, dim 2) + 32->64->8 ReLU MLP, 8-corner
// trilinear blend.  One thread per (point, outer corner); 8 threads/point are
// consecutive lanes -> shuffle reduction + coalesced store.
//
// R1 changes vs 395.8us baseline:
//  * hashed levels 7..15 fully unrolled via templates (compile-time R/O) ->
//    deeper vmcnt pipelining across levels instead of 9 serialized stalls
//  * __launch_bounds__(256,5): 5 waves/SIMD (VGPR<=102), LDS 5x32KB = 160KB/CU
//  * MLP hidden chunked h[16]x4 to keep MLP-phase VGPR low (w1/w2 are s_loads)
//  All arithmetic bit-identical to the passing baseline.
// ---------------------------------------------------------------------------

#define BLK 256

// Finest level resolution: ceil(16 * scale^15), 16*scale^15 == 513.0 +- ~1e-12
// in float64.  513 is the intended value (DESIRED_RES).  If the bench fails
// with absmax ~0.05-0.3 (level-15-only corruption), flip this to 514.
#define R15 513

// Linear (tight-grid) level: compile-time R/H/O so % H becomes magic-multiply.
template <int R, int H, int O>
__device__ __forceinline__ void enc_linear(float xcx, float xcy, float xcz,
                                           const float2* __restrict__ tab,
                                           float& f0, float& f1) {
    const float Rf = (float)R;
    // replicate reference op order: pos = x*R + 0.5 (no fma contraction)
    float px = __fadd_rn(__fmul_rn(xcx, Rf), 0.5f);
    float py = __fadd_rn(__fmul_rn(xcy, Rf), 0.5f);
    float pz = __fadd_rn(__fmul_rn(xcz, Rf), 0.5f);
    float fpx = floorf(px), fpy = floorf(py), fpz = floorf(pz);
    float frx = px - fpx, fry = py - fpy, frz = pz - fpz;
    int gx = (int)fpx, gy = (int)fpy, gz = (int)fpz;
    float wx[2] = {1.f - frx, frx};
    float wy[2] = {1.f - fry, fry};
    float wz[2] = {1.f - frz, frz};
    // hand-CSE the index terms (integer-exact, identical results)
    const int R1 = R + 1;
    int xt[2] = {gx, gx + 1};
    int yt[2] = {gy * R1, gy * R1 + R1};
    int zt[2] = {gz * R1 * R1, gz * R1 * R1 + R1 * R1};
    float a0 = 0.f, a1 = 0.f;
#pragma unroll
    for (int c = 0; c < 8; ++c) {  // corner order (x,y,z) = bits (2,1,0): matches CORNERS
        const int ox = (c >> 2) & 1, oy = (c >> 1) & 1, oz = c & 1;
        int id  = xt[ox] + yt[oy] + zt[oz];
        int idx = (int)((uint32_t)id % (uint32_t)H);  // reference applies % H even on tight grids
        float w = wx[ox] * wy[oy] * wz[oz];
        float2 tv = tab[O + idx];
        a0 = fmaf(w, tv.x, a0);
        a1 = fmaf(w, tv.y, a1);
    }
    f0 = a0; f1 = a1;
}

// Hashed level (H = 2^19): compile-time R/O, hand-CSE'd hash terms.
template <int RI, int O>
__device__ __forceinline__ void enc_hash(float xcx, float xcy, float xcz,
                                         const float2* __restrict__ tab,
                                         float& f0, float& f1) {
    const float Rf = (float)RI;
    float px = __fadd_rn(__fmul_rn(xcx, Rf), 0.5f);
    float py = __fadd_rn(__fmul_rn(xcy, Rf), 0.5f);
    float pz = __fadd_rn(__fmul_rn(xcz, Rf), 0.5f);
    float fpx = floorf(px), fpy = floorf(py), fpz = floorf(pz);
    float frx = px - fpx, fry = py - fpy, frz = pz - fpz;
    uint32_t gx = (uint32_t)(int)fpx, gy = (uint32_t)(int)fpy, gz = (uint32_t)(int)fpz;
    float wx[2] = {1.f - frx, frx};
    float wy[2] = {1.f - fry, fry};
    float wz[2] = {1.f - frz, frz};
    // instant-NGP fast_hash primes {1, 2654435761, 805459861}; CSE the 8 muls
    uint32_t xt[2] = {gx, gx + 1u};
    uint32_t yt[2] = {gy * 2654435761u, gy * 2654435761u + 2654435761u};
    uint32_t zt[2] = {gz * 805459861u,  gz * 805459861u  + 805459861u};
    float a0 = 0.f, a1 = 0.f;
#pragma unroll
    for (int c = 0; c < 8; ++c) {
        const int ox = (c >> 2) & 1, oy = (c >> 1) & 1, oz = c & 1;
        uint32_t idx = (xt[ox] ^ yt[oy] ^ zt[oz]) & 524287u;
        float w = wx[ox] * wy[oy] * wz[oz];
        float2 tv = tab[O + (int)idx];
        a0 = fmaf(w, tv.x, a0);
        a1 = fmaf(w, tv.y, a1);
    }
    f0 = a0; f1 = a1;
}

__global__ __launch_bounds__(BLK, 5)
void grid_fused(const float* __restrict__ xyz, const float* __restrict__ bound,
                const float* __restrict__ table, const float* __restrict__ w1,
                const float* __restrict__ w2, float* __restrict__ out, int N) {
    // feats staged in LDS: layout [feat][thread] -> consecutive lanes hit
    // consecutive banks (2 lanes/bank for wave64 = free).  Each thread only
    // reads back its own 32 feats (LDS used as cheap register extension).
    __shared__ float sfeat[32 * BLK];

    const int tid = threadIdx.x;
    const int t = blockIdx.x * BLK + tid;
    const int p = t >> 3;
    const int a = t & 7;
    if (p >= N) return;

    const float2* tab = (const float2*)table;

    const float b = bound[0];
    float X = xyz[3 * p + 0], Y = xyz[3 * p + 1], Z = xyz[3 * p + 2];
    // x = (xyz + bound) / (2*bound); coords = x * 512
    float cx = ((X + b) / (2.0f * b)) * 512.0f;
    float cy = ((Y + b) / (2.0f * b)) * 512.0f;
    float cz = ((Z + b) / (2.0f * b)) * 512.0f;
    float c0x = fmaxf(fminf(floorf(cx), 511.f), 0.f);
    float c0y = fmaxf(fminf(floorf(cy), 511.f), 0.f);
    float c0z = fmaxf(fminf(floorf(cz), 511.f), 0.f);
    float uu = cx - c0x, vv = cy - c0y, wwf = cz - c0z;  // outer trilinear fracs

    const int ax = (a >> 2) & 1, ay = (a >> 1) & 1, az = a & 1;  // CORNERS order
    // encode-space coordinate of this outer corner: (c0+a)/512, exact
    float xcx = (c0x + (float)ax) * (1.0f / 512.0f);
    float xcy = (c0y + (float)ay) * (1.0f / 512.0f);
    float xcz = (c0z + (float)az) * (1.0f / 512.0f);

    // ---- linear levels 0..6 (straight-line) --------------------------------
    float f0, f1;
    enc_linear<16,   4920,      0>(xcx, xcy, xcz, tab, f0, f1); sfeat[ 0*BLK+tid]=f0; sfeat[ 1*BLK+tid]=f1;
    enc_linear<21,  10648,   4920>(xcx, xcy, xcz, tab, f0, f1); sfeat[ 2*BLK+tid]=f0; sfeat[ 3*BLK+tid]=f1;
    enc_linear<26,  19688,  15568>(xcx, xcy, xcz, tab, f0, f1); sfeat[ 4*BLK+tid]=f0; sfeat[ 5*BLK+tid]=f1;
    enc_linear<33,  39304,  35256>(xcx, xcy, xcz, tab, f0, f1); sfeat[ 6*BLK+tid]=f0; sfeat[ 7*BLK+tid]=f1;
    enc_linear<41,  74088,  74560>(xcx, xcy, xcz, tab, f0, f1); sfeat[ 8*BLK+tid]=f0; sfeat[ 9*BLK+tid]=f1;
    enc_linear<51, 140608, 148648>(xcx, xcy, xcz, tab, f0, f1); sfeat[10*BLK+tid]=f0; sfeat[11*BLK+tid]=f1;
    enc_linear<65, 287496, 289256>(xcx, xcy, xcz, tab, f0, f1); sfeat[12*BLK+tid]=f0; sfeat[13*BLK+tid]=f1;

    // ---- hashed levels 7..15 (H = 2^19), fully unrolled --------------------
    enc_hash< 81,  576752>(xcx, xcy, xcz, tab, f0, f1); sfeat[14*BLK+tid]=f0; sfeat[15*BLK+tid]=f1;
    enc_hash<102, 1101040>(xcx, xcy, xcz, tab, f0, f1); sfeat[16*BLK+tid]=f0; sfeat[17*BLK+tid]=f1;
    enc_hash<129, 1625328>(xcx, xcy, xcz, tab, f0, f1); sfeat[18*BLK+tid]=f0; sfeat[19*BLK+tid]=f1;
    enc_hash<162, 2149616>(xcx, xcy, xcz, tab, f0, f1); sfeat[20*BLK+tid]=f0; sfeat[21*BLK+tid]=f1;
    enc_hash<204, 2673904>(xcx, xcy, xcz, tab, f0, f1); sfeat[22*BLK+tid]=f0; sfeat[23*BLK+tid]=f1;
    enc_hash<257, 3198192>(xcx, xcy, xcz, tab, f0, f1); sfeat[24*BLK+tid]=f0; sfeat[25*BLK+tid]=f1;
    enc_hash<324, 3722480>(xcx, xcy, xcz, tab, f0, f1); sfeat[26*BLK+tid]=f0; sfeat[27*BLK+tid]=f1;
    enc_hash<408, 4246768>(xcx, xcy, xcz, tab, f0, f1); sfeat[28*BLK+tid]=f0; sfeat[29*BLK+tid]=f1;
    enc_hash<R15, 4771056>(xcx, xcy, xcz, tab, f0, f1); sfeat[30*BLK+tid]=f0; sfeat[31*BLK+tid]=f1;

    // ---- MLP: relu(feats @ w1) @ w2, hidden dim in four 16-reg chunks ------
    // w1/w2 row pointers are wave-uniform -> s_load; inner FMA is v_fmac(v,s,v)
    float acc[8] = {0.f, 0.f, 0.f, 0.f, 0.f, 0.f, 0.f, 0.f};
#pragma unroll 1
    for (int kb = 0; kb < 64; kb += 16) {
        float h[16];
#pragma unroll
        for (int k = 0; k < 16; ++k) h[k] = 0.f;
#pragma unroll 1
        for (int i = 0; i < 32; ++i) {
            float fi = sfeat[i * BLK + tid];
            const float* wr = w1 + i * 64 + kb;  // wave-uniform -> s_load
#pragma unroll
            for (int k = 0; k < 16; ++k) h[k] = fmaf(fi, wr[k], h[k]);
        }
#pragma unroll
        for (int k = 0; k < 16; ++k) {
            float hk = fmaxf(h[k], 0.f);
            const float* w2r = w2 + (kb + k) * 8;  // wave-uniform -> s_load
#pragma unroll
            for (int j = 0; j < 8; ++j) acc[j] = fmaf(hk, w2r[j], acc[j]);
        }
    }

    // ---- outer trilinear weight + 8-lane reduction --------------------------
    float wt = (ax ? uu : 1.f - uu) * (ay ? vv : 1.f - vv) * (az ? wwf : 1.f - wwf);
#pragma unroll
    for (int j = 0; j < 8; ++j) {
        float v = acc[j] * wt;
        v += __shfl_xor(v, 1);
        v += __shfl_xor(v, 2);
        v += __shfl_xor(v, 4);
        acc[j] = v;  // all 8 lanes now hold the full sum for output j
    }
    // lane a writes output column a -> out[p*8 + a] == out[t], fully coalesced
    float r01 = (a & 1) ? acc[1] : acc[0];
    float r23 = (a & 1) ? acc[3] : acc[2];
    float r45 = (a & 1) ? acc[5] : acc[4];
    float r67 = (a & 1) ? acc[7] : acc[6];
    float r03 = (a & 2) ? r23 : r01;
    float r47 = (a & 2) ? r67 : r45;
    float r   = (a & 4) ? r47 : r03;
    out[t] = r;
}

extern "C" void kernel_launch(void* const* d_in, const int* in_sizes, int n_in,
                              void* d_out, int out_size, void* d_ws, size_t ws_size,
                              hipStream_t stream) {
    const float* xyz   = (const float*)d_in[0];
    const float* bound = (const float*)d_in[1];
    const float* table = (const float*)d_in[2];
    const float* w1    = (const float*)d_in[3];
    const float* w2    = (const float*)d_in[4];
    float* out = (float*)d_out;

    const int N = in_sizes[0] / 3;          // 262144
    const int threads = N * 8;              // one thread per (point, corner)
    const int blocks = (threads + BLK - 1) / BLK;
    grid_fused<<<blocks, BLK, 0, stream>>>(xyz, bound, table, w1, w2, out, N);
}

// Round 2
// 405.396 us; speedup vs baseline: 1.0203x; 1.0203x over previous
//
#include <hip/hip_runtime.h>
#include <stdint.h>

// ---------------------------------------------------------------------------
// torch-ngp hashgrid encode (16 levels, dim 2) + 32->64->8 ReLU MLP, 8-corner
// trilinear blend.  One thread per (point, outer corner); 8 threads/point are
// consecutive lanes -> shuffle reduction + coalesced store.
//
// R2 changes vs R1 (346us, VALUBusy 57%, Occ 43%, LDS-capped):
//  * feats held in 32 VGPRs instead of a 32KB LDS buffer (each thread only
//    ever re-read its own values -> LDS was pure overhead + occupancy cap)
//  * __launch_bounds__(256,6): 6 waves/SIMD budget (85 VGPR), no LDS limit
//  * MLP i-loop fully unrolled so all fr[] indices are compile-time (keeps
//    the array in registers, not scratch)
//  All arithmetic bit-identical to the passing R1 kernel.
// ---------------------------------------------------------------------------

#define BLK 256

// Finest level resolution: ceil(16 * scale^15), 16*scale^15 == 513.0 +- ~1e-12
// in float64.  513 is the intended value (DESIRED_RES).
#define R15 513

// Linear (tight-grid) level: compile-time R/H/O so % H becomes magic-multiply.
template <int R, int H, int O>
__device__ __forceinline__ void enc_linear(float xcx, float xcy, float xcz,
                                           const float2* __restrict__ tab,
                                           float& f0, float& f1) {
    const float Rf = (float)R;
    // replicate reference op order: pos = x*R + 0.5 (no fma contraction)
    float px = __fadd_rn(__fmul_rn(xcx, Rf), 0.5f);
    float py = __fadd_rn(__fmul_rn(xcy, Rf), 0.5f);
    float pz = __fadd_rn(__fmul_rn(xcz, Rf), 0.5f);
    float fpx = floorf(px), fpy = floorf(py), fpz = floorf(pz);
    float frx = px - fpx, fry = py - fpy, frz = pz - fpz;
    int gx = (int)fpx, gy = (int)fpy, gz = (int)fpz;
    float wx[2] = {1.f - frx, frx};
    float wy[2] = {1.f - fry, fry};
    float wz[2] = {1.f - frz, frz};
    // hand-CSE the index terms (integer-exact, identical results)
    const int R1 = R + 1;
    int xt[2] = {gx, gx + 1};
    int yt[2] = {gy * R1, gy * R1 + R1};
    int zt[2] = {gz * R1 * R1, gz * R1 * R1 + R1 * R1};
    float a0 = 0.f, a1 = 0.f;
#pragma unroll
    for (int c = 0; c < 8; ++c) {  // corner order (x,y,z) = bits (2,1,0): matches CORNERS
        const int ox = (c >> 2) & 1, oy = (c >> 1) & 1, oz = c & 1;
        int id  = xt[ox] + yt[oy] + zt[oz];
        int idx = (int)((uint32_t)id % (uint32_t)H);  // reference applies % H even on tight grids
        float w = wx[ox] * wy[oy] * wz[oz];
        float2 tv = tab[O + idx];
        a0 = fmaf(w, tv.x, a0);
        a1 = fmaf(w, tv.y, a1);
    }
    f0 = a0; f1 = a1;
}

// Hashed level (H = 2^19): compile-time R/O, hand-CSE'd hash terms.
template <int RI, int O>
__device__ __forceinline__ void enc_hash(float xcx, float xcy, float xcz,
                                         const float2* __restrict__ tab,
                                         float& f0, float& f1) {
    const float Rf = (float)RI;
    float px = __fadd_rn(__fmul_rn(xcx, Rf), 0.5f);
    float py = __fadd_rn(__fmul_rn(xcy, Rf), 0.5f);
    float pz = __fadd_rn(__fmul_rn(xcz, Rf), 0.5f);
    float fpx = floorf(px), fpy = floorf(py), fpz = floorf(pz);
    float frx = px - fpx, fry = py - fpy, frz = pz - fpz;
    uint32_t gx = (uint32_t)(int)fpx, gy = (uint32_t)(int)fpy, gz = (uint32_t)(int)fpz;
    float wx[2] = {1.f - frx, frx};
    float wy[2] = {1.f - fry, fry};
    float wz[2] = {1.f - frz, frz};
    // instant-NGP fast_hash primes {1, 2654435761, 805459861}; CSE the 8 muls
    uint32_t xt[2] = {gx, gx + 1u};
    uint32_t yt[2] = {gy * 2654435761u, gy * 2654435761u + 2654435761u};
    uint32_t zt[2] = {gz * 805459861u,  gz * 805459861u  + 805459861u};
    float a0 = 0.f, a1 = 0.f;
#pragma unroll
    for (int c = 0; c < 8; ++c) {
        const int ox = (c >> 2) & 1, oy = (c >> 1) & 1, oz = c & 1;
        uint32_t idx = (xt[ox] ^ yt[oy] ^ zt[oz]) & 524287u;
        float w = wx[ox] * wy[oy] * wz[oz];
        float2 tv = tab[O + (int)idx];
        a0 = fmaf(w, tv.x, a0);
        a1 = fmaf(w, tv.y, a1);
    }
    f0 = a0; f1 = a1;
}

__global__ __launch_bounds__(BLK, 6)
void grid_fused(const float* __restrict__ xyz, const float* __restrict__ bound,
                const float* __restrict__ table, const float* __restrict__ w1,
                const float* __restrict__ w2, float* __restrict__ out, int N) {
    const int tid = threadIdx.x;
    const int t = blockIdx.x * BLK + tid;
    const int p = t >> 3;
    const int a = t & 7;
    if (p >= N) return;

    const float2* tab = (const float2*)table;

    const float b = bound[0];
    float X = xyz[3 * p + 0], Y = xyz[3 * p + 1], Z = xyz[3 * p + 2];
    // x = (xyz + bound) / (2*bound); coords = x * 512
    float cx = ((X + b) / (2.0f * b)) * 512.0f;
    float cy = ((Y + b) / (2.0f * b)) * 512.0f;
    float cz = ((Z + b) / (2.0f * b)) * 512.0f;
    float c0x = fmaxf(fminf(floorf(cx), 511.f), 0.f);
    float c0y = fmaxf(fminf(floorf(cy), 511.f), 0.f);
    float c0z = fmaxf(fminf(floorf(cz), 511.f), 0.f);
    float uu = cx - c0x, vv = cy - c0y, wwf = cz - c0z;  // outer trilinear fracs

    const int ax = (a >> 2) & 1, ay = (a >> 1) & 1, az = a & 1;  // CORNERS order
    // encode-space coordinate of this outer corner: (c0+a)/512, exact
    float xcx = (c0x + (float)ax) * (1.0f / 512.0f);
    float xcy = (c0y + (float)ay) * (1.0f / 512.0f);
    float xcz = (c0z + (float)az) * (1.0f / 512.0f);

    // ---- all 16 levels -> 32 feature registers -----------------------------
    float fr[32];
    enc_linear<16,   4920,      0>(xcx, xcy, xcz, tab, fr[ 0], fr[ 1]);
    enc_linear<21,  10648,   4920>(xcx, xcy, xcz, tab, fr[ 2], fr[ 3]);
    enc_linear<26,  19688,  15568>(xcx, xcy, xcz, tab, fr[ 4], fr[ 5]);
    enc_linear<33,  39304,  35256>(xcx, xcy, xcz, tab, fr[ 6], fr[ 7]);
    enc_linear<41,  74088,  74560>(xcx, xcy, xcz, tab, fr[ 8], fr[ 9]);
    enc_linear<51, 140608, 148648>(xcx, xcy, xcz, tab, fr[10], fr[11]);
    enc_linear<65, 287496, 289256>(xcx, xcy, xcz, tab, fr[12], fr[13]);
    enc_hash< 81,  576752>(xcx, xcy, xcz, tab, fr[14], fr[15]);
    enc_hash<102, 1101040>(xcx, xcy, xcz, tab, fr[16], fr[17]);
    enc_hash<129, 1625328>(xcx, xcy, xcz, tab, fr[18], fr[19]);
    enc_hash<162, 2149616>(xcx, xcy, xcz, tab, fr[20], fr[21]);
    enc_hash<204, 2673904>(xcx, xcy, xcz, tab, fr[22], fr[23]);
    enc_hash<257, 3198192>(xcx, xcy, xcz, tab, fr[24], fr[25]);
    enc_hash<324, 3722480>(xcx, xcy, xcz, tab, fr[26], fr[27]);
    enc_hash<408, 4246768>(xcx, xcy, xcz, tab, fr[28], fr[29]);
    enc_hash<R15, 4771056>(xcx, xcy, xcz, tab, fr[30], fr[31]);

    // ---- MLP: relu(feats @ w1) @ w2, hidden dim in four 16-reg chunks ------
    // fr[] fully register-resident: i-loop is fully unrolled so every index
    // is compile-time (rule: runtime-indexed arrays go to scratch).
    // w1/w2 row pointers are wave-uniform -> s_load; FMA is v_fmac(v,s,v).
    // Accumulation order identical to R1 (hidden units ascending 0..63).
    float acc[8] = {0.f, 0.f, 0.f, 0.f, 0.f, 0.f, 0.f, 0.f};
#pragma unroll 1
    for (int kb = 0; kb < 64; kb += 16) {
        float h[16];
#pragma unroll
        for (int k = 0; k < 16; ++k) h[k] = 0.f;
#pragma unroll
        for (int i = 0; i < 32; ++i) {
            const float* wr = w1 + i * 64 + kb;  // wave-uniform -> s_load
#pragma unroll
            for (int k = 0; k < 16; ++k) h[k] = fmaf(fr[i], wr[k], h[k]);
        }
#pragma unroll
        for (int k = 0; k < 16; ++k) {
            float hk = fmaxf(h[k], 0.f);
            const float* w2r = w2 + (kb + k) * 8;  // wave-uniform -> s_load
#pragma unroll
            for (int j = 0; j < 8; ++j) acc[j] = fmaf(hk, w2r[j], acc[j]);
        }
    }

    // ---- outer trilinear weight + 8-lane reduction --------------------------
    float wt = (ax ? uu : 1.f - uu) * (ay ? vv : 1.f - vv) * (az ? wwf : 1.f - wwf);
#pragma unroll
    for (int j = 0; j < 8; ++j) {
        float v = acc[j] * wt;
        v += __shfl_xor(v, 1);
        v += __shfl_xor(v, 2);
        v += __shfl_xor(v, 4);
        acc[j] = v;  // all 8 lanes now hold the full sum for output j
    }
    // lane a writes output column a -> out[p*8 + a] == out[t], fully coalesced
    float r01 = (a & 1) ? acc[1] : acc[0];
    float r23 = (a & 1) ? acc[3] : acc[2];
    float r45 = (a & 1) ? acc[5] : acc[4];
    float r67 = (a & 1) ? acc[7] : acc[6];
    float r03 = (a & 2) ? r23 : r01;
    float r47 = (a & 2) ? r67 : r45;
    float r   = (a & 4) ? r47 : r03;
    out[t] = r;
}

extern "C" void kernel_launch(void* const* d_in, const int* in_sizes, int n_in,
                              void* d_out, int out_size, void* d_ws, size_t ws_size,
                              hipStream_t stream) {
    const float* xyz   = (const float*)d_in[0];
    const float* bound = (const float*)d_in[1];
    const float* table = (const float*)d_in[2];
    const float* w1    = (const float*)d_in[3];
    const float* w2    = (const float*)d_in[4];
    float* out = (float*)d_out;

    const int N = in_sizes[0] / 3;          // 262144
    const int threads = N * 8;              // one thread per (point, corner)
    const int blocks = (threads + BLK - 1) / BLK;
    grid_fused<<<blocks, BLK, 0, stream>>>(xyz, bound, table, w1, w2, out, N);
}